// Round 1
// baseline (47.693 us; speedup 1.0000x reference)
//
#include <hip/hip_runtime.h>

#define TPB 192            // 3 waves; one per channel in phase 2
#define NG 1024            // float4 granules per channel tile (8 rows * 128)
#define CH_STRIDE4 65536   // 512*512/4 float4s per channel plane

static __device__ __forceinline__ void fma4(float4& a, float s, const float4& v) {
    a.x = fmaf(s, v.x, a.x);
    a.y = fmaf(s, v.y, a.y);
    a.z = fmaf(s, v.z, a.z);
    a.w = fmaf(s, v.w, a.w);
}

__global__ __launch_bounds__(TPB) void jpeg_fused(
    const float* __restrict__ img,
    const float* __restrict__ Dd,
    const float* __restrict__ Di,
    const float* __restrict__ mask,
    float* __restrict__ out)
{
    // YUV staging: [3][8 rows][128 granules], granule-XOR swizzled. 48 KB.
    __shared__ float4 lds[3 * NG];

    const int tid = threadIdx.x;
    const int wg  = blockIdx.x;
    const int b   = wg >> 6;     // batch index
    const int rb  = wg & 63;     // block-row index (8-row strip)

    // float4 index of this tile's channel-0 plane start (tile is contiguous per channel)
    const size_t tbase = ((size_t)b * 3 * 512 + (size_t)rb * 8) * 512 / 4;
    const float4* in4  = reinterpret_cast<const float4*>(img) + tbase;
    float4*       out4 = reinterpret_cast<float4*>(out) + tbase;

    // ---------------- Phase 1: RGB -> YUV into LDS ----------------
    for (int g = tid; g < NG; g += TPB) {
        float4 R  = in4[g];
        float4 G  = in4[CH_STRIDE4 + g];
        float4 Bv = in4[2 * CH_STRIDE4 + g];
        float4 Y, U, V;
        Y.x = 0.299f*R.x + 0.587f*G.x + 0.114f*Bv.x;
        Y.y = 0.299f*R.y + 0.587f*G.y + 0.114f*Bv.y;
        Y.z = 0.299f*R.z + 0.587f*G.z + 0.114f*Bv.z;
        Y.w = 0.299f*R.w + 0.587f*G.w + 0.114f*Bv.w;
        U.x = -0.14713f*R.x - 0.28886f*G.x + 0.436f*Bv.x;
        U.y = -0.14713f*R.y - 0.28886f*G.y + 0.436f*Bv.y;
        U.z = -0.14713f*R.z - 0.28886f*G.z + 0.436f*Bv.z;
        U.w = -0.14713f*R.w - 0.28886f*G.w + 0.436f*Bv.w;
        V.x = 0.615f*R.x - 0.51499f*G.x - 0.10001f*Bv.x;
        V.y = 0.615f*R.y - 0.51499f*G.y - 0.10001f*Bv.y;
        V.z = 0.615f*R.z - 0.51499f*G.z - 0.10001f*Bv.z;
        V.w = 0.615f*R.w - 0.51499f*G.w - 0.10001f*Bv.w;
        // swizzle granule within its row: flip bit0 when bit3 set -> balances b128 bank groups
        const int gi = (g & ~127) + ((g & 127) ^ ((g >> 3) & 1));
        lds[gi]          = Y;
        lds[NG + gi]     = U;
        lds[2 * NG + gi] = V;
    }
    __syncthreads();

    // ---------------- Phase 2: per-thread 8x8 block DCT -> mask -> IDCT ----------------
    {
        const int c   = tid >> 6;   // wave-uniform channel
        const int blk = tid & 63;   // block column 0..63
        const int cs  = __builtin_amdgcn_readfirstlane(c);
        const float* __restrict__ M = mask + (size_t)cs * (512 * 512); // top-left 8x8 = tile pattern
        float4* plane = lds + c * NG;

        const int sw = (blk >> 2) & 1;
        const int g0 = (2 * blk) ^ sw;
        const int g1 = (2 * blk + 1) ^ sw;

        float4 xlo[8], xhi[8];
        #pragma unroll
        for (int r = 0; r < 8; ++r) {
            xlo[r] = plane[r * 128 + g0];
            xhi[r] = plane[r * 128 + g1];
        }

        // DCT: Z = Dd * X * Dd^T, then mask
        float4 zlo[8], zhi[8];
        #pragma unroll
        for (int k = 0; k < 8; ++k) {
            float4 tlo = make_float4(0.f, 0.f, 0.f, 0.f);
            float4 thi = make_float4(0.f, 0.f, 0.f, 0.f);
            #pragma unroll
            for (int n = 0; n < 8; ++n) {
                const float d = Dd[k * 8 + n];
                fma4(tlo, d, xlo[n]);
                fma4(thi, d, xhi[n]);
            }
            const float t[8] = {tlo.x, tlo.y, tlo.z, tlo.w, thi.x, thi.y, thi.z, thi.w};
            float z[8];
            #pragma unroll
            for (int l = 0; l < 8; ++l) {
                float acc = 0.f;
                #pragma unroll
                for (int m = 0; m < 8; ++m) acc = fmaf(t[m], Dd[l * 8 + m], acc);
                z[l] = acc * M[k * 512 + l];
            }
            zlo[k] = make_float4(z[0], z[1], z[2], z[3]);
            zhi[k] = make_float4(z[4], z[5], z[6], z[7]);
        }

        // IDCT: Y' = Di * Z * Di^T, write back in place (thread owns its block)
        #pragma unroll
        for (int k = 0; k < 8; ++k) {
            float4 tlo = make_float4(0.f, 0.f, 0.f, 0.f);
            float4 thi = make_float4(0.f, 0.f, 0.f, 0.f);
            #pragma unroll
            for (int n = 0; n < 8; ++n) {
                const float d = Di[k * 8 + n];
                fma4(tlo, d, zlo[n]);
                fma4(thi, d, zhi[n]);
            }
            const float t[8] = {tlo.x, tlo.y, tlo.z, tlo.w, thi.x, thi.y, thi.z, thi.w};
            float z[8];
            #pragma unroll
            for (int l = 0; l < 8; ++l) {
                float acc = 0.f;
                #pragma unroll
                for (int m = 0; m < 8; ++m) acc = fmaf(t[m], Di[l * 8 + m], acc);
                z[l] = acc;
            }
            plane[k * 128 + g0] = make_float4(z[0], z[1], z[2], z[3]);
            plane[k * 128 + g1] = make_float4(z[4], z[5], z[6], z[7]);
        }
    }
    __syncthreads();

    // ---------------- Phase 3: YUV -> RGB, store ----------------
    for (int g = tid; g < NG; g += TPB) {
        const int gi = (g & ~127) + ((g & 127) ^ ((g >> 3) & 1));
        float4 Y = lds[gi];
        float4 U = lds[NG + gi];
        float4 V = lds[2 * NG + gi];
        float4 R, G, Bv;
        R.x = Y.x + 1.13983f*V.x;  R.y = Y.y + 1.13983f*V.y;
        R.z = Y.z + 1.13983f*V.z;  R.w = Y.w + 1.13983f*V.w;
        G.x = Y.x - 0.39465f*U.x - 0.5806f*V.x;
        G.y = Y.y - 0.39465f*U.y - 0.5806f*V.y;
        G.z = Y.z - 0.39465f*U.z - 0.5806f*V.z;
        G.w = Y.w - 0.39465f*U.w - 0.5806f*V.w;
        Bv.x = Y.x + 2.03211f*U.x; Bv.y = Y.y + 2.03211f*U.y;
        Bv.z = Y.z + 2.03211f*U.z; Bv.w = Y.w + 2.03211f*U.w;
        out4[g]                  = R;
        out4[CH_STRIDE4 + g]     = G;
        out4[2 * CH_STRIDE4 + g] = Bv;
    }
}

extern "C" void kernel_launch(void* const* d_in, const int* in_sizes, int n_in,
                              void* d_out, int out_size, void* d_ws, size_t ws_size,
                              hipStream_t stream) {
    const float* img  = (const float*)d_in[0];
    const float* Dd   = (const float*)d_in[1];
    const float* Di   = (const float*)d_in[2];
    const float* mask = (const float*)d_in[3];
    float* out = (float*)d_out;

    const int B = in_sizes[0] / (3 * 512 * 512);   // 32
    dim3 grid(B * 64);                              // one wg per (batch, 8-row strip)
    dim3 block(TPB);
    hipLaunchKernelGGL(jpeg_fused, grid, block, 0, stream, img, Dd, Di, mask, out);
}